// Round 3
// baseline (46254.114 us; speedup 1.0000x reference)
//
#include <hip/hip_runtime.h>
#include <math.h>

// Problem constants
#define Bn 256
#define Tn 128
#define En 768
#define HEn 256
#define Hn 512
#define SLOTn 120
#define INTENTn 64
#define EMBn 40
#define NEGV -1e12f

__device__ __forceinline__ float sigm(float x) { return 1.0f / (1.0f + expf(-x)); }

// ---------------------------------------------------------------------------
// zero init for recurrent state buffers
__global__ void zero_k(float* __restrict__ p, int n) {
    int i = blockIdx.x * blockDim.x + threadIdx.x;
    int stride = gridDim.x * blockDim.x;
    for (; i < n; i += stride) p[i] = 0.f;
}

// ---------------------------------------------------------------------------
// Detect mask dtype: jax bool may arrive as u8 (1B) or widened to int32 (4B).
// If ANY byte at offset %4 != 0 within the first 32KB is nonzero, it must be
// u8 (int32 0/1 little-endian has those bytes all zero). Writes flag: 1=u8.
__global__ void detect_mask_k(const unsigned char* __restrict__ m, int* __restrict__ flag) {
    __shared__ int any;
    if (threadIdx.x == 0) any = 0;
    __syncthreads();
    int found = 0;
    for (int i = threadIdx.x; i < 32768; i += 256) {
        if ((i & 3) != 0 && m[i] != 0) found = 1;
    }
    if (found) atomicOr(&any, 1);
    __syncthreads();
    if (threadIdx.x == 0) *flag = any;
}

// ---------------------------------------------------------------------------
// Encoder: one timestep, both directions. Fused x@Wih + h@Whh GEMM (K=1024)
// with gate-ordered columns so the LSTM update is applied in-kernel.
// Tile: 32 rows(b) x 64 cols (16 jl x 4 gates). K-tile=32 (barrier halving).
// grid (16, 8, 2)
__global__ __launch_bounds__(256) void enc_step_k(
    const float* __restrict__ seq,
    const float* __restrict__ Wf_ih, const float* __restrict__ Wf_hh,
    const float* __restrict__ bf_ih, const float* __restrict__ bf_hh,
    const float* __restrict__ Wb_ih, const float* __restrict__ Wb_hh,
    const float* __restrict__ bb_ih, const float* __restrict__ bb_hh,
    const float* __restrict__ hf_in, float* __restrict__ hf_out, float* __restrict__ cf,
    const float* __restrict__ hb_in, float* __restrict__ hb_out, float* __restrict__ cb,
    float* __restrict__ enc, int step)
{
    const int dir = blockIdx.z;
    const float* Wih = dir ? Wb_ih : Wf_ih;
    const float* Whh = dir ? Wb_hh : Wf_hh;
    const float* bih = dir ? bb_ih : bf_ih;
    const float* bhh = dir ? bb_hh : bf_hh;
    const float* h_in = dir ? hb_in : hf_in;
    float* h_out = dir ? hb_out : hf_out;
    float* c_st  = dir ? cb : cf;
    const int t_eff = dir ? (Tn - 1 - step) : step;
    const int nb = blockIdx.x;          // 16 tiles of 16 jl
    const int b0 = blockIdx.y << 5;     // 32-row tiles
    const int tid = threadIdx.x;
    const int tx = tid & 15, ty = tid >> 4;

    __shared__ float As[32][36];
    __shared__ float Bs[32][68];
    __shared__ float Gs[32][68];

    float acc[2][4] = {};

    for (int kt = 0; kt < 32; ++kt) {   // K = 768 (x) + 256 (h), 32-wide tiles
        const int k0 = kt << 5;
#pragma unroll
        for (int r = 0; r < 4; ++r) {
            int idx = tid + (r << 8);
            int kk = idx & 31, row = idx >> 5;
            int k = k0 + kk, b = b0 + row;
            As[kk][row] = (k < En) ? seq[((size_t)b * Tn + t_eff) * En + k]
                                   : h_in[(b << 8) + (k - En)];
        }
#pragma unroll
        for (int r = 0; r < 8; ++r) {
            int idx = tid + (r << 8);
            int kk = idx & 31, c = idx >> 5;
            int j = ((c >> 4) << 8) + (nb << 4) + (c & 15);  // gate*256 + jl
            int k = k0 + kk;
            Bs[kk][c] = (k < En) ? Wih[j * En + k] : Whh[(j << 8) + (k - En)];
        }
        __syncthreads();
#pragma unroll
        for (int kk = 0; kk < 32; ++kk) {
            float a0 = As[kk][ty * 2], a1 = As[kk][ty * 2 + 1];
            float w0 = Bs[kk][tx * 4], w1 = Bs[kk][tx * 4 + 1];
            float w2 = Bs[kk][tx * 4 + 2], w3 = Bs[kk][tx * 4 + 3];
            acc[0][0] += a0 * w0; acc[0][1] += a0 * w1; acc[0][2] += a0 * w2; acc[0][3] += a0 * w3;
            acc[1][0] += a1 * w0; acc[1][1] += a1 * w1; acc[1][2] += a1 * w2; acc[1][3] += a1 * w3;
        }
        __syncthreads();
    }

#pragma unroll
    for (int i = 0; i < 2; ++i)
#pragma unroll
        for (int q = 0; q < 4; ++q)
            Gs[ty * 2 + i][tx * 4 + q] = acc[i][q];
    __syncthreads();

#pragma unroll
    for (int r = 0; r < 2; ++r) {
        int p = tid + (r << 8);
        int row = p >> 4, jl = p & 15;
        int jg = (nb << 4) + jl;
        int b = b0 + row;
        float gi = Gs[row][jl]      + bih[jg]           + bhh[jg];
        float gf = Gs[row][16 + jl] + bih[HEn + jg]     + bhh[HEn + jg];
        float gg = Gs[row][32 + jl] + bih[2 * HEn + jg] + bhh[2 * HEn + jg];
        float go = Gs[row][48 + jl] + bih[3 * HEn + jg] + bhh[3 * HEn + jg];
        float ii = sigm(gi), ff = sigm(gf), tg = tanhf(gg), oo = sigm(go);
        int ci = (b << 8) + jg;
        float cn = ff * c_st[ci] + ii * tg;
        float hn = oo * tanhf(cn);
        c_st[ci] = cn;
        h_out[ci] = hn;
        enc[((size_t)t_eff * Bn + b) * Hn + dir * HEn + jg] = hn;
    }
}

// ---------------------------------------------------------------------------
// energiesT[b][j][t] = sum_k enc[t][b][k] * attn_W[j][k]   (attn_b dropped:
// it adds a t'-constant shift inside softmax -> invariant)
// grid (8, 512): nb = j-tile, mb -> (t, b-tile). K-tile=32.
__global__ __launch_bounds__(256) void energT_k(
    const float* __restrict__ enc, const float* __restrict__ attn_W,
    float* __restrict__ energT)
{
    const int nb = blockIdx.x;
    const int mb = blockIdx.y;
    const int t = mb >> 2, b0 = (mb & 3) << 6;
    const int tid = threadIdx.x;
    const int tx = tid & 15, ty = tid >> 4;
    __shared__ float As[32][68];
    __shared__ float Bs[32][68];
    float acc[4][4] = {};
    for (int kt = 0; kt < 16; ++kt) {   // K = 512
        int k0 = kt << 5;
#pragma unroll
        for (int r = 0; r < 8; ++r) {
            int idx = tid + (r << 8);
            int kk = idx & 31, row = idx >> 5;
            As[kk][row] = enc[((size_t)t * Bn + b0 + row) * Hn + k0 + kk];
            Bs[kk][row] = attn_W[(nb * 64 + row) * Hn + k0 + kk];
        }
        __syncthreads();
#pragma unroll
        for (int kk = 0; kk < 32; ++kk) {
            float a0 = As[kk][ty * 4], a1 = As[kk][ty * 4 + 1];
            float a2 = As[kk][ty * 4 + 2], a3 = As[kk][ty * 4 + 3];
            float w0 = Bs[kk][tx * 4], w1 = Bs[kk][tx * 4 + 1];
            float w2 = Bs[kk][tx * 4 + 2], w3 = Bs[kk][tx * 4 + 3];
            acc[0][0] += a0 * w0; acc[0][1] += a0 * w1; acc[0][2] += a0 * w2; acc[0][3] += a0 * w3;
            acc[1][0] += a1 * w0; acc[1][1] += a1 * w1; acc[1][2] += a1 * w2; acc[1][3] += a1 * w3;
            acc[2][0] += a2 * w0; acc[2][1] += a2 * w1; acc[2][2] += a2 * w2; acc[2][3] += a2 * w3;
            acc[3][0] += a3 * w0; acc[3][1] += a3 * w1; acc[3][2] += a3 * w2; acc[3][3] += a3 * w3;
        }
        __syncthreads();
    }
#pragma unroll
    for (int i = 0; i < 4; ++i)
#pragma unroll
        for (int q = 0; q < 4; ++q)
            energT[((size_t)(b0 + ty * 4 + i) * Hn + nb * 64 + tx * 4 + q) * Tn + t] = acc[i][q];
}

// ---------------------------------------------------------------------------
// After encoder: count nonzero nwp, gather last_hidden into ctx0, init emb=BOS
__global__ __launch_bounds__(64) void init2_k(
    const int* __restrict__ nwp, const float* __restrict__ enc,
    const float* __restrict__ emb_table,
    float* __restrict__ ctx0, float* __restrict__ embb)
{
    int b = blockIdx.x;
    int lane = threadIdx.x;
    int p1 = (nwp[b * Tn + lane] != 0);
    int p2 = (nwp[b * Tn + lane + 64] != 0);
    unsigned long long m1 = __ballot(p1), m2 = __ballot(p2);
    int cnt = __popcll(m1) + __popcll(m2);
    int idx = cnt < (Tn - 1) ? cnt : (Tn - 1);
#pragma unroll
    for (int r = 0; r < 8; ++r) {
        int j = lane + (r << 6);
        ctx0[(b << 9) + j] = enc[((size_t)idx * Bn + b) * Hn + j];
    }
    if (lane < EMBn) embb[b * EMBn + lane] = emb_table[SLOTn * EMBn + lane];
}

// ---------------------------------------------------------------------------
// Decoder LSTM step: G = [emb|ctx|enc_t|h] @ [Wd_ih|Wd_hh].T, gates fused.
// Tile 32 x 64 (16 jl x 4 gates), K = 1576 (50 tiles of 32, tail zero-padded).
// grid (32, 8)
__global__ __launch_bounds__(256) void dec_step_k(
    const float* __restrict__ embb, const float* __restrict__ ctx_in,
    const float* __restrict__ enc, const float* __restrict__ h_in,
    float* __restrict__ h_out, float* __restrict__ c_st,
    const float* __restrict__ Wih, const float* __restrict__ Whh,
    const float* __restrict__ bih, const float* __restrict__ bhh,
    float* __restrict__ h0_out, int step)
{
    const int nb = blockIdx.x;          // 32 tiles of 16 jl
    const int b0 = blockIdx.y << 5;
    const int tid = threadIdx.x;
    const int tx = tid & 15, ty = tid >> 4;

    __shared__ float As[32][36];
    __shared__ float Bs[32][68];
    __shared__ float Gs[32][68];

    float acc[2][4] = {};

    for (int kt = 0; kt < 50; ++kt) {   // 50 * 32 = 1600 >= 1576, tail padded
        const int k0 = kt << 5;
#pragma unroll
        for (int r = 0; r < 4; ++r) {
            int idx = tid + (r << 8);
            int kk = idx & 31, row = idx >> 5;
            int k = k0 + kk, b = b0 + row;
            float v = 0.f;
            if (k < 40) v = embb[b * EMBn + k];
            else if (k < 552) v = ctx_in[(b << 9) + (k - 40)];
            else if (k < 1064) v = enc[((size_t)step * Bn + b) * Hn + (k - 552)];
            else if (k < 1576) v = h_in[(b << 9) + (k - 1064)];
            As[kk][row] = v;
        }
#pragma unroll
        for (int r = 0; r < 8; ++r) {
            int idx = tid + (r << 8);
            int kk = idx & 31, c = idx >> 5;
            int j = ((c >> 4) << 9) + (nb << 4) + (c & 15);  // gate*512 + jl
            int k = k0 + kk;
            float w = 0.f;
            if (k < 1064) w = Wih[(size_t)j * 1064 + k];
            else if (k < 1576) w = Whh[(j << 9) + (k - 1064)];
            Bs[kk][c] = w;
        }
        __syncthreads();
#pragma unroll
        for (int kk = 0; kk < 32; ++kk) {
            float a0 = As[kk][ty * 2], a1 = As[kk][ty * 2 + 1];
            float w0 = Bs[kk][tx * 4], w1 = Bs[kk][tx * 4 + 1];
            float w2 = Bs[kk][tx * 4 + 2], w3 = Bs[kk][tx * 4 + 3];
            acc[0][0] += a0 * w0; acc[0][1] += a0 * w1; acc[0][2] += a0 * w2; acc[0][3] += a0 * w3;
            acc[1][0] += a1 * w0; acc[1][1] += a1 * w1; acc[1][2] += a1 * w2; acc[1][3] += a1 * w3;
        }
        __syncthreads();
    }

#pragma unroll
    for (int i = 0; i < 2; ++i)
#pragma unroll
        for (int q = 0; q < 4; ++q)
            Gs[ty * 2 + i][tx * 4 + q] = acc[i][q];
    __syncthreads();

#pragma unroll
    for (int r = 0; r < 2; ++r) {
        int p = tid + (r << 8);
        int row = p >> 4, jl = p & 15;
        int jg = (nb << 4) + jl;
        int b = b0 + row;
        float gi = Gs[row][jl]      + bih[jg]          + bhh[jg];
        float gf = Gs[row][16 + jl] + bih[Hn + jg]     + bhh[Hn + jg];
        float gg = Gs[row][32 + jl] + bih[2 * Hn + jg] + bhh[2 * Hn + jg];
        float go = Gs[row][48 + jl] + bih[3 * Hn + jg] + bhh[3 * Hn + jg];
        float ii = sigm(gi), ff = sigm(gf), tg = tanhf(gg), oo = sigm(go);
        int ci = (b << 9) + jg;
        float cn = ff * c_st[ci] + ii * tg;
        float hn = oo * tanhf(cn);
        c_st[ci] = cn;
        h_out[ci] = hn;
        if (h0_out) h0_out[ci] = hn;
    }
}

// ---------------------------------------------------------------------------
// Fused per-step: blocks [0,256) attention (per-b), blocks [256,288) slot head
// (8 b each). Attention reads h (post-LSTM) only; slot reads h + ctx_in.
__global__ __launch_bounds__(256) void dec_attn_slot_k(
    const float* __restrict__ enc, const float* __restrict__ energT,
    const float* __restrict__ h, const float* __restrict__ ctx_in,
    float* __restrict__ ctx_out, const unsigned char* __restrict__ mask_u8,
    const int* __restrict__ mask_i32, const int* __restrict__ mask_flag,
    const float* __restrict__ slot_W, const float* __restrict__ slot_b,
    const float* __restrict__ emb_table, float* __restrict__ embb,
    float* __restrict__ out_slot, float* __restrict__ ctx0_save, int step)
{
    __shared__ float hs[512];
    __shared__ float red[256];
    __shared__ float es[128];
    __shared__ float ins[8][1032];
    __shared__ float Ws[16][132];
    __shared__ float sc[8][132];
    __shared__ float logZ[8];
    __shared__ int amax[8];

    const int bid = blockIdx.x;
    const int tid = threadIdx.x;

    if (bid < Bn) {
        // ---- attention for batch b ----
        const int b = bid;
        hs[tid] = h[(b << 9) + tid];
        hs[tid + 256] = h[(b << 9) + 256 + tid];
        __syncthreads();
        const int tp = tid & 127, half = tid >> 7;
        const float* ept = energT + ((size_t)b * Hn + (half << 8)) * Tn + tp;
        const float* hp = hs + (half << 8);
        float acc = 0.f;
#pragma unroll 8
        for (int j = 0; j < 256; ++j) acc += ept[(size_t)j * Tn] * hp[j];
        red[tid] = acc;
        __syncthreads();
        if (tid < 128) {
            float e = red[tid] + red[tid + 128];
            bool mv = (*mask_flag) ? (mask_u8[(size_t)b * Tn + tid] != 0)
                                   : (mask_i32[(size_t)b * Tn + tid] != 0);
            if (mv) e = NEGV;
            es[tid] = e;
        }
        __syncthreads();
        if (tid < 64) {
            float v = fmaxf(es[tid], es[tid + 64]);
            for (int o = 32; o; o >>= 1) v = fmaxf(v, __shfl_down(v, o));
            if (tid == 0) red[0] = v;
        }
        __syncthreads();
        float m = red[0];
        if (tid < 128) es[tid] = __expf(es[tid] - m);
        __syncthreads();
        if (tid < 64) {
            float v = es[tid] + es[tid + 64];
            for (int o = 32; o; o >>= 1) v += __shfl_down(v, o);
            if (tid == 0) red[0] = v;
        }
        __syncthreads();
        float inv = 1.0f / red[0];
        if (tid < 128) es[tid] *= inv;
        __syncthreads();
        float c0 = 0.f, c1 = 0.f;
        const float* ep = enc + (b << 9) + tid;
#pragma unroll 4
        for (int t2 = 0; t2 < Tn; ++t2) {
            float a = es[t2];
            c0 += a * ep[(size_t)t2 * Bn * Hn];
            c1 += a * ep[(size_t)t2 * Bn * Hn + 256];
        }
        ctx_out[(b << 9) + tid] = c0;
        ctx_out[(b << 9) + tid + 256] = c1;
        if (ctx0_save) {
            ctx0_save[(b << 9) + tid] = c0;
            ctx0_save[(b << 9) + tid + 256] = c1;
        }
    } else {
        // ---- slot head for 8 batches ----
        const int b_base = (bid - Bn) << 3;
        for (int r = 0; r < 32; ++r) {
            int idx = tid + (r << 8);
            int bl = idx >> 10, k = idx & 1023;
            int b = b_base + bl;
            ins[bl][k] = (k < 512) ? h[(b << 9) + k] : ctx_in[(b << 9) + (k - 512)];
        }
        __syncthreads();
        const int s = tid & 127, bh = tid >> 7;
        float acc[4] = {};
        for (int kt = 0; kt < 64; ++kt) {
            int k0 = kt << 4;
#pragma unroll
            for (int r = 0; r < 8; ++r) {
                int idx = tid + (r << 8);
                int kk = idx & 15, ss = idx >> 4;
                Ws[kk][ss] = (ss < SLOTn) ? slot_W[ss * 1024 + k0 + kk] : 0.f;
            }
            __syncthreads();
#pragma unroll
            for (int kk = 0; kk < 16; ++kk) {
                float w = Ws[kk][s];
#pragma unroll
                for (int i = 0; i < 4; ++i) acc[i] += w * ins[(bh << 2) + i][k0 + kk];
            }
            __syncthreads();
        }
        if (s < SLOTn) {
#pragma unroll
            for (int i = 0; i < 4; ++i) sc[(bh << 2) + i][s] = acc[i] + slot_b[s];
        }
        __syncthreads();
        if (tid < 8) {
            float mm = -INFINITY; int am = 0;
            for (int ss = 0; ss < SLOTn; ++ss) {
                float v = sc[tid][ss];
                if (v > mm) { mm = v; am = ss; }
            }
            float sum = 0.f;
            for (int ss = 0; ss < SLOTn; ++ss) sum += __expf(sc[tid][ss] - mm);
            logZ[tid] = mm + logf(sum);
            amax[tid] = am;
        }
        __syncthreads();
        for (int r = 0; r < 4; ++r) {
            int idx = tid + (r << 8);
            int bl = idx >> 7, ss = idx & 127;
            if (ss < SLOTn)
                out_slot[(size_t)(b_base + bl) * Tn * SLOTn + step * SLOTn + ss] =
                    sc[bl][ss] - logZ[bl];
        }
        // NOTE: 8*EMBn = 320 > blockDim (256) -> must stride-loop (bugfix R1)
        for (int i = tid; i < 8 * EMBn; i += 256) {
            int bl = i / EMBn, e2 = i % EMBn;
            embb[(b_base + bl) * EMBn + e2] = emb_table[amax[bl] * EMBn + e2];
        }
    }
}

// ---------------------------------------------------------------------------
// intent_score = [h0|ctx0] @ intent_W.T + intent_b ; 32 blocks x 8 b
__global__ __launch_bounds__(256) void intent_k(
    const float* __restrict__ h0, const float* __restrict__ ctx0,
    const float* __restrict__ W, const float* __restrict__ bias,
    float* __restrict__ out)
{
    __shared__ float ins[8][1032];
    __shared__ float Ws[16][68];
    const int tid = threadIdx.x;
    const int b_base = blockIdx.x << 3;
    for (int r = 0; r < 32; ++r) {
        int idx = tid + (r << 8);
        int bl = idx >> 10, k = idx & 1023;
        int b = b_base + bl;
        ins[bl][k] = (k < 512) ? h0[(b << 9) + k] : ctx0[(b << 9) + (k - 512)];
    }
    __syncthreads();
    const int n = tid & 63, bq = tid >> 6;
    float acc0 = 0.f, acc1 = 0.f;
    for (int kt = 0; kt < 64; ++kt) {
        int k0 = kt << 4;
#pragma unroll
        for (int r = 0; r < 4; ++r) {
            int idx = tid + (r << 8);
            int kk = idx & 15, nn = idx >> 4;
            Ws[kk][nn] = W[nn * 1024 + k0 + kk];
        }
        __syncthreads();
#pragma unroll
        for (int kk = 0; kk < 16; ++kk) {
            float w = Ws[kk][n];
            acc0 += w * ins[bq * 2][k0 + kk];
            acc1 += w * ins[bq * 2 + 1][k0 + kk];
        }
        __syncthreads();
    }
    out[(b_base + bq * 2) * INTENTn + n] = acc0 + bias[n];
    out[(b_base + bq * 2 + 1) * INTENTn + n] = acc1 + bias[n];
}

// ---------------------------------------------------------------------------
extern "C" void kernel_launch(void* const* d_in, const int* in_sizes, int n_in,
                              void* d_out, int out_size, void* d_ws, size_t ws_size,
                              hipStream_t stream) {
    (void)in_sizes; (void)n_in; (void)out_size; (void)ws_size;

    const float* seq      = (const float*)d_in[0];
    const int*   nwp      = (const int*)d_in[1];
    const unsigned char* mask_u8 = (const unsigned char*)d_in[2];
    const int*   mask_i32 = (const int*)d_in[2];
    const float* embt     = (const float*)d_in[3];
    const float* Wf_ih    = (const float*)d_in[4];
    const float* Wf_hh    = (const float*)d_in[5];
    const float* bf_ih    = (const float*)d_in[6];
    const float* bf_hh    = (const float*)d_in[7];
    const float* Wb_ih    = (const float*)d_in[8];
    const float* Wb_hh    = (const float*)d_in[9];
    const float* bb_ih    = (const float*)d_in[10];
    const float* bb_hh    = (const float*)d_in[11];
    const float* Wd_ih    = (const float*)d_in[12];
    const float* Wd_hh    = (const float*)d_in[13];
    const float* bd_ih    = (const float*)d_in[14];
    const float* bd_hh    = (const float*)d_in[15];
    const float* attn_W   = (const float*)d_in[16];
    // d_in[17] = attn_b: provably unused (softmax shift invariance)
    const float* slot_W   = (const float*)d_in[18];
    const float* slot_b   = (const float*)d_in[19];
    const float* intent_W = (const float*)d_in[20];
    const float* intent_b = (const float*)d_in[21];

    float* Wp = (float*)d_ws;
    size_t off = 0;
    float* enc    = Wp + off; off += (size_t)Tn * Bn * Hn;   // [T,B,512]
    float* energT = Wp + off; off += (size_t)Bn * Hn * Tn;   // [B,512,T]
    float* zbase  = Wp + off;                                 // zeroed region:
    float* hf0 = Wp + off; off += Bn * HEn;
    float* hf1 = Wp + off; off += Bn * HEn;
    float* cf  = Wp + off; off += Bn * HEn;
    float* hb0 = Wp + off; off += Bn * HEn;
    float* hb1 = Wp + off; off += Bn * HEn;
    float* cb  = Wp + off; off += Bn * HEn;
    float* hd0 = Wp + off; off += Bn * Hn;
    float* hd1 = Wp + off; off += Bn * Hn;
    float* cd  = Wp + off; off += Bn * Hn;
    int nzero = (int)(Wp + off - zbase);                      // 786432 floats
    float* ctx0b = Wp + off; off += Bn * Hn;
    float* ctx1b = Wp + off; off += Bn * Hn;
    float* h0s   = Wp + off; off += Bn * Hn;
    float* ctx0s = Wp + off; off += Bn * Hn;
    float* embb  = Wp + off; off += Bn * EMBn;
    int* mask_flag = (int*)(Wp + off); off += 1;
    // total ~139.5 MB of workspace

    float* out = (float*)d_out;

    zero_k<<<512, 256, 0, stream>>>(zbase, nzero);
    detect_mask_k<<<1, 256, 0, stream>>>(mask_u8, mask_flag);

    // -------- encoder (128 steps, both directions per launch) --------
    for (int s = 0; s < Tn; ++s) {
        const float* hinf = (s & 1) ? hf1 : hf0;
        float* houtf      = (s & 1) ? hf0 : hf1;
        const float* hinb = (s & 1) ? hb1 : hb0;
        float* houtb      = (s & 1) ? hb0 : hb1;
        enc_step_k<<<dim3(16, 8, 2), 256, 0, stream>>>(
            seq, Wf_ih, Wf_hh, bf_ih, bf_hh, Wb_ih, Wb_hh, bb_ih, bb_hh,
            hinf, houtf, cf, hinb, houtb, cb, enc, s);
    }

    energT_k<<<dim3(8, 512), 256, 0, stream>>>(enc, attn_W, energT);
    init2_k<<<256, 64, 0, stream>>>(nwp, enc, embt, ctx0b, embb);

    // -------- decoder (128 steps) --------
    for (int t = 0; t < Tn; ++t) {
        const float* ctxin = (t & 1) ? ctx1b : ctx0b;
        float* ctxout      = (t & 1) ? ctx0b : ctx1b;
        const float* hin   = (t & 1) ? hd1 : hd0;
        float* hout        = (t & 1) ? hd0 : hd1;
        dec_step_k<<<dim3(32, 8), 256, 0, stream>>>(
            embb, ctxin, enc, hin, hout, cd,
            Wd_ih, Wd_hh, bd_ih, bd_hh, (t == 0) ? h0s : (float*)nullptr, t);
        dec_attn_slot_k<<<288, 256, 0, stream>>>(
            enc, energT, hout, ctxin, ctxout, mask_u8, mask_i32, mask_flag,
            slot_W, slot_b, embt, embb, out, (t == 0) ? ctx0s : (float*)nullptr, t);
    }

    intent_k<<<32, 256, 0, stream>>>(h0s, ctx0s, intent_W, intent_b,
                                     out + (size_t)Bn * Tn * SLOTn);
}